// Round 2
// baseline (10860.061 us; speedup 1.0000x reference)
//
#include <hip/hip_runtime.h>
#include <math.h>

// Problem constants
constexpr int V  = 32000;
constexpr int D  = 1024;
constexpr int L  = 6;
constexpr int H  = 16;
constexpr int DH = 64;
constexpr int B  = 2;
constexpr int N  = 1024;
constexpr int M  = B * N; // 2048 token rows

// ---------------------------------------------------------------------------
// Embedding gather: X[row,:] = emb[tokens[row],:]
// ---------------------------------------------------------------------------
__global__ __launch_bounds__(256) void gather_kernel(const int* __restrict__ tokens,
                                                     const float* __restrict__ emb,
                                                     float* __restrict__ X) {
    int row = blockIdx.x;
    int t = threadIdx.x;
    int tok = tokens[row];
    ((float4*)(X + (size_t)row * D))[t] = ((const float4*)(emb + (size_t)tok * D))[t];
}

// ---------------------------------------------------------------------------
// RMSNorm (exact ref semantics: inv = rsqrt(sum(x^2)+1e-12); out = x*inv*sqrt(D)*gamma)
// one block per row, 256 threads, 1 float4/thread
// ---------------------------------------------------------------------------
__global__ __launch_bounds__(256) void rmsnorm_kernel(const float* __restrict__ X,
                                                      const float* __restrict__ gamma,
                                                      float* __restrict__ O) {
    int row = blockIdx.x;
    int t = threadIdx.x;
    float4 x = ((const float4*)(X + (size_t)row * D))[t];
    float ss = x.x * x.x + x.y * x.y + x.z * x.z + x.w * x.w;
#pragma unroll
    for (int off = 32; off; off >>= 1) ss += __shfl_xor(ss, off);
    __shared__ float red[4];
    int w = t >> 6;
    if ((t & 63) == 0) red[w] = ss;
    __syncthreads();
    ss = red[0] + red[1] + red[2] + red[3];
    float inv = rsqrtf(ss + 1e-12f) * 32.0f; // sqrt(1024)=32
    float4 g = ((const float4*)gamma)[t];
    float4 o;
    o.x = x.x * inv * g.x;
    o.y = x.y * inv * g.y;
    o.z = x.z * inv * g.z;
    o.w = x.w * inv * g.w;
    ((float4*)(O + (size_t)row * D))[t] = o;
}

// ---------------------------------------------------------------------------
// Tiled fp32 GEMM: C[M,N] = A[M,K] @ W[K,N]
// BM=BN=128, BK=16, 256 threads, 8x8 per thread in 4-corner (2x2 of float4) layout
// EPI: 0 = store, 1 = C += result (residual), 2 = gelu(result)
// ---------------------------------------------------------------------------
#define GBM 128
#define GBN 128
#define GBK 16
template <int EPI>
__global__ __launch_bounds__(256) void gemm_kernel(const float* __restrict__ A,
                                                   const float* __restrict__ Bw,
                                                   float* __restrict__ C,
                                                   int Mdim, int Ndim, int Kdim) {
    __shared__ float As[GBK][GBM + 4]; // padded: 2-way-max conflicts on transposed store
    __shared__ float Bs[GBK][GBN];
    int t = threadIdx.x;
    int tx = t & 15, ty = t >> 4;
    int m0 = blockIdx.y * GBM, n0 = blockIdx.x * GBN;

    float acc[8][8];
#pragma unroll
    for (int i = 0; i < 8; i++)
#pragma unroll
        for (int j = 0; j < 8; j++) acc[i][j] = 0.f;

    for (int k0 = 0; k0 < Kdim; k0 += GBK) {
        // Load A tile (128x16) as 512 float4, 2/thread; store transposed As[k][m]
#pragma unroll
        for (int i = 0; i < 2; i++) {
            int idx = t + i * 256;
            int r = idx >> 2, c4 = idx & 3;
            float4 a = *(const float4*)(A + (size_t)(m0 + r) * Kdim + k0 + c4 * 4);
            As[c4 * 4 + 0][r] = a.x;
            As[c4 * 4 + 1][r] = a.y;
            As[c4 * 4 + 2][r] = a.z;
            As[c4 * 4 + 3][r] = a.w;
        }
        // Load B tile (16x128) as 512 float4, 2/thread
#pragma unroll
        for (int i = 0; i < 2; i++) {
            int idx = t + i * 256;
            int r = idx >> 5, c4 = idx & 31;
            *(float4*)&Bs[r][c4 * 4] = *(const float4*)(Bw + (size_t)(k0 + r) * Ndim + n0 + c4 * 4);
        }
        __syncthreads();
#pragma unroll
        for (int k = 0; k < GBK; k++) {
            float4 a0 = *(const float4*)&As[k][ty * 4];
            float4 a1 = *(const float4*)&As[k][ty * 4 + 64];
            float4 b0 = *(const float4*)&Bs[k][tx * 4];
            float4 b1 = *(const float4*)&Bs[k][tx * 4 + 64];
            float av[8] = {a0.x, a0.y, a0.z, a0.w, a1.x, a1.y, a1.z, a1.w};
            float bv[8] = {b0.x, b0.y, b0.z, b0.w, b1.x, b1.y, b1.z, b1.w};
#pragma unroll
            for (int i = 0; i < 8; i++)
#pragma unroll
                for (int j = 0; j < 8; j++) acc[i][j] = fmaf(av[i], bv[j], acc[i][j]);
        }
        __syncthreads();
    }
    // Epilogue: rows m0 + ty*4 + ih*64 + i, cols n0 + tx*4 + jh*64
#pragma unroll
    for (int ih = 0; ih < 2; ih++)
#pragma unroll
        for (int i = 0; i < 4; i++) {
            int r = m0 + ty * 4 + ih * 64 + i;
            float* crow = C + (size_t)r * Ndim;
#pragma unroll
            for (int jh = 0; jh < 2; jh++) {
                int cc = n0 + tx * 4 + jh * 64;
                float4 v;
                v.x = acc[ih * 4 + i][jh * 4 + 0];
                v.y = acc[ih * 4 + i][jh * 4 + 1];
                v.z = acc[ih * 4 + i][jh * 4 + 2];
                v.w = acc[ih * 4 + i][jh * 4 + 3];
                if (EPI == 1) {
                    float4 o = *(const float4*)(crow + cc);
                    v.x += o.x; v.y += o.y; v.z += o.z; v.w += o.w;
                } else if (EPI == 2) {
                    v.x = 0.5f * v.x * (1.f + erff(v.x * 0.70710678118654752f));
                    v.y = 0.5f * v.y * (1.f + erff(v.y * 0.70710678118654752f));
                    v.z = 0.5f * v.z * (1.f + erff(v.z * 0.70710678118654752f));
                    v.w = 0.5f * v.w * (1.f + erff(v.w * 0.70710678118654752f));
                }
                *(float4*)(crow + cc) = v;
            }
        }
}

// ---------------------------------------------------------------------------
// RoPE + split heads: QKV (M x 3072) -> Qh, Kh (rotated), Vh in (B*H, N, DH) layout
// ---------------------------------------------------------------------------
__global__ __launch_bounds__(256) void rope_split_kernel(const float* __restrict__ QKV,
                                                         float* __restrict__ Qh,
                                                         float* __restrict__ Kh,
                                                         float* __restrict__ Vh) {
    int row = blockIdx.x; // b*N + n
    int n = row & (N - 1);
    int b = row >> 10;
    int t = threadIdx.x;
    const float* src = QKV + (size_t)row * (3 * D);

    // V copy: thread t moves float4 t of the v block
    {
        float4 v4 = ((const float4*)(src + 2 * D))[t];
        int h = t >> 4;
        int d = (t & 15) * 4;
        *(float4*)(Vh + ((size_t)(b * H + h) * N + n) * DH + d) = v4;
    }
    // q,k rope: 512 pairs each, thread handles 2 of each
#pragma unroll
    for (int i = 0; i < 2; i++) {
        int p = t + i * 256; // 0..511
        int hh = p >> 5;
        int pi = p & 31;
        float inv = powf(10000.0f, -(float)pi / 32.0f);
        float ang = (float)n * inv;
        float s, c;
        sincosf(ang, &s, &c);
        {
            float q0 = src[hh * DH + 2 * pi];
            float q1 = src[hh * DH + 2 * pi + 1];
            float* qd = Qh + ((size_t)(b * H + hh) * N + n) * DH;
            qd[2 * pi]     = q0 * c - q1 * s;
            qd[2 * pi + 1] = q1 * c + q0 * s;
        }
        {
            float k0 = src[D + hh * DH + 2 * pi];
            float k1 = src[D + hh * DH + 2 * pi + 1];
            float* kd = Kh + ((size_t)(b * H + hh) * N + n) * DH;
            kd[2 * pi]     = k0 * c - k1 * s;
            kd[2 * pi + 1] = k1 * c + k0 * s;
        }
    }
}

// ---------------------------------------------------------------------------
// Attention: per block = one (b,h) and a tile of TQ=8 q rows, full softmax over N keys.
// Scores staged in LDS (8x1024 = 32KB).
// ---------------------------------------------------------------------------
__global__ __launch_bounds__(256) void attn_kernel(const float* __restrict__ Q,
                                                   const float* __restrict__ K,
                                                   const float* __restrict__ Vv,
                                                   float* __restrict__ O) {
    constexpr int TQ = 8;
    __shared__ float qs[TQ][DH];   // 2KB
    __shared__ float sc[TQ][N];    // 32KB
    __shared__ float rs[TQ];
    int bh = blockIdx.y;
    int n0 = blockIdx.x * TQ;
    int t = threadIdx.x;
    const float* Qb = Q + ((size_t)bh * N + n0) * DH;
    const float* Kb = K + (size_t)bh * N * DH;
    const float* Vb = Vv + (size_t)bh * N * DH;

    if (t < TQ * DH / 4) ((float4*)qs)[t] = ((const float4*)Qb)[t];
    __syncthreads();

    // --- scores: thread handles keys t*4 .. t*4+3 (two pairs) ---
#pragma unroll
    for (int kp = 0; kp < 2; kp++) {
        int j0 = t * 4 + kp * 2;
        const float4* k0p = (const float4*)(Kb + (size_t)j0 * DH);
        const float4* k1p = k0p + (DH / 4);
        float acc0[TQ], acc1[TQ];
#pragma unroll
        for (int r = 0; r < TQ; r++) { acc0[r] = 0.f; acc1[r] = 0.f; }
#pragma unroll
        for (int dc = 0; dc < DH / 4; dc++) {
            float4 kv0 = k0p[dc];
            float4 kv1 = k1p[dc];
#pragma unroll
            for (int r = 0; r < TQ; r++) {
                float4 q4 = *(const float4*)&qs[r][dc * 4];
                acc0[r] = fmaf(q4.x, kv0.x, fmaf(q4.y, kv0.y, fmaf(q4.z, kv0.z, fmaf(q4.w, kv0.w, acc0[r]))));
                acc1[r] = fmaf(q4.x, kv1.x, fmaf(q4.y, kv1.y, fmaf(q4.z, kv1.z, fmaf(q4.w, kv1.w, acc1[r]))));
            }
        }
#pragma unroll
        for (int r = 0; r < TQ; r++) {
            sc[r][j0] = acc0[r] * 0.125f;
            sc[r][j0 + 1] = acc1[r] * 0.125f;
        }
    }
    __syncthreads();

    // --- softmax: 32 threads per row ---
    {
        int r = t >> 5, g = t & 31;
        float4* srow = (float4*)&sc[r][0];
        float mx = -1e30f;
#pragma unroll
        for (int c = 0; c < 8; c++) {
            float4 v = srow[g + c * 32];
            mx = fmaxf(mx, fmaxf(fmaxf(v.x, v.y), fmaxf(v.z, v.w)));
        }
#pragma unroll
        for (int off = 16; off; off >>= 1) mx = fmaxf(mx, __shfl_xor(mx, off, 32));
        float sum = 0.f;
#pragma unroll
        for (int c = 0; c < 8; c++) {
            float4 v = srow[g + c * 32];
            v.x = __expf(v.x - mx);
            v.y = __expf(v.y - mx);
            v.z = __expf(v.z - mx);
            v.w = __expf(v.w - mx);
            sum += v.x + v.y + v.z + v.w;
            srow[g + c * 32] = v;
        }
#pragma unroll
        for (int off = 16; off; off >>= 1) sum += __shfl_xor(sum, off, 32);
        if (g == 0) rs[r] = sum;
    }
    __syncthreads();

    // --- out = P @ V: thread owns d = t&63, rows {w, w+4} ---
    {
        int d = t & 63, w = t >> 6;
        float a0 = 0.f, a1 = 0.f;
        for (int jc = 0; jc < N / 4; jc++) {
            float4 p0 = *(const float4*)&sc[w][jc * 4];
            float4 p1 = *(const float4*)&sc[w + 4][jc * 4];
            const float* vp = Vb + (size_t)jc * 4 * DH + d;
            float v0 = vp[0], v1 = vp[DH], v2 = vp[2 * DH], v3 = vp[3 * DH];
            a0 += p0.x * v0 + p0.y * v1 + p0.z * v2 + p0.w * v3;
            a1 += p1.x * v0 + p1.y * v1 + p1.z * v2 + p1.w * v3;
        }
        O[((size_t)bh * N + n0 + w) * DH + d] = a0 / rs[w];
        O[((size_t)bh * N + n0 + w + 4) * DH + d] = a1 / rs[w + 4];
    }
}

// ---------------------------------------------------------------------------
// retrieve(feat, mem_kv, mem_norm) with elu(x)+1 applied on the fly.
// MODE 0: out(B,N,D layout) = ATT*g + retrieve(qf)*(1-g)   (gate fusion)
// MODE 1: out(head layout)  = V - retrieve(kf)             (v2 for delta rule)
// grid: (N/64, B*H)
// ---------------------------------------------------------------------------
template <int MODE>
__global__ __launch_bounds__(256) void retrieve_kernel(const float* __restrict__ F,
                                                       const float* __restrict__ mem_kv,
                                                       const float* __restrict__ mem_norm,
                                                       const float* __restrict__ AuxIn,
                                                       const float* __restrict__ gates_l,
                                                       float* __restrict__ outp) {
    int bh = blockIdx.y;
    int n0 = blockIdx.x * 64;
    int b = bh / H, h = bh % H;
    __shared__ float mk[DH][DH];  // 16KB
    __shared__ float ff[64][DH];  // 16KB
    __shared__ float mn[DH], den[64];
    int t = threadIdx.x;

#pragma unroll
    for (int i = 0; i < 4; i++) {
        int idx = t + i * 256;
        float4 v = ((const float4*)(mem_kv + (size_t)bh * DH * DH))[idx];
        *(float4*)&mk[idx >> 4][(idx & 15) * 4] = v;
    }
    if (t < DH / 4) ((float4*)mn)[t] = ((const float4*)(mem_norm + (size_t)bh * DH))[t];
#pragma unroll
    for (int i = 0; i < 4; i++) {
        int idx = t + i * 256;
        int r = idx >> 4, c4 = (idx & 15) * 4;
        float4 v = *(const float4*)(F + ((size_t)bh * N + n0 + r) * DH + c4);
        v.x = v.x > 0.f ? v.x + 1.f : __expf(v.x);  // elu(x)+1
        v.y = v.y > 0.f ? v.y + 1.f : __expf(v.y);
        v.z = v.z > 0.f ? v.z + 1.f : __expf(v.z);
        v.w = v.w > 0.f ? v.w + 1.f : __expf(v.w);
        *(float4*)&ff[r][c4] = v;
    }
    __syncthreads();
    if (t < 64) {
        float s = 0.f;
        for (int dd = 0; dd < DH; dd++) s += ff[t][dd] * mn[dd];
        den[t] = fmaxf(s, 1e-10f);
    }
    __syncthreads();

    int e = t & 63, w = t >> 6;
    float g = 0.f;
    if (MODE == 0) g = 1.f / (1.f + __expf(-gates_l[h]));
#pragma unroll 4
    for (int i = 0; i < 16; i++) {
        int nn = w + i * 4;
        float acc = 0.f;
        for (int dd = 0; dd < DH; dd++) acc = fmaf(ff[nn][dd], mk[dd][e], acc);
        float val = acc / den[nn];
        if (MODE == 0) {
            float a = AuxIn[((size_t)bh * N + n0 + nn) * DH + e];
            outp[((size_t)(b * N + n0 + nn)) * D + h * DH + e] = a * g + val * (1.f - g);
        } else {
            float vv = AuxIn[((size_t)bh * N + n0 + nn) * DH + e];
            outp[((size_t)bh * N + n0 + nn) * DH + e] = vv - val;
        }
    }
}

// ---------------------------------------------------------------------------
// new_kv partials: for n-chunk of 64, compute kf^T @ v2 (64x64) and sum_n kf
// grid: (16, 32)
// ---------------------------------------------------------------------------
__global__ __launch_bounds__(256) void newkv_partial_kernel(const float* __restrict__ Kh,
                                                            const float* __restrict__ V2,
                                                            float* __restrict__ part,
                                                            float* __restrict__ partn) {
    int bh = blockIdx.y;
    int chunk = blockIdx.x;
    int n0 = chunk * 64;
    __shared__ float kf[64][DH];
    __shared__ float vs[64][DH];
    int t = threadIdx.x;
#pragma unroll
    for (int i = 0; i < 4; i++) {
        int idx = t + i * 256;
        int r = idx >> 4, c4 = (idx & 15) * 4;
        float4 v = *(const float4*)(Kh + ((size_t)bh * N + n0 + r) * DH + c4);
        v.x = v.x > 0.f ? v.x + 1.f : __expf(v.x);
        v.y = v.y > 0.f ? v.y + 1.f : __expf(v.y);
        v.z = v.z > 0.f ? v.z + 1.f : __expf(v.z);
        v.w = v.w > 0.f ? v.w + 1.f : __expf(v.w);
        *(float4*)&kf[r][c4] = v;
        float4 u = *(const float4*)(V2 + ((size_t)bh * N + n0 + r) * DH + c4);
        *(float4*)&vs[r][c4] = u;
    }
    __syncthreads();
    int e = t & 63, w = t >> 6;
    int d0 = w * 16;
    float acc[16];
#pragma unroll
    for (int i = 0; i < 16; i++) acc[i] = 0.f;
    for (int nn = 0; nn < 64; nn++) {
        float vv = vs[nn][e];
#pragma unroll
        for (int i = 0; i < 16; i++) acc[i] = fmaf(kf[nn][d0 + i], vv, acc[i]);
    }
    float* pp = part + ((size_t)bh * 16 + chunk) * DH * DH;
#pragma unroll
    for (int i = 0; i < 16; i++) pp[(size_t)(d0 + i) * DH + e] = acc[i];
    if (t < 64) {
        float s = 0.f;
        for (int nn = 0; nn < 64; nn++) s += kf[nn][t];
        partn[((size_t)bh * 16 + chunk) * DH + t] = s;
    }
}

// ---------------------------------------------------------------------------
// reduce partials + past -> outputs. grid: 32 blocks (bh)
// ---------------------------------------------------------------------------
__global__ __launch_bounds__(256) void kv_reduce_kernel(const float* __restrict__ part,
                                                        const float* __restrict__ partn,
                                                        const float* __restrict__ past_kv_l,
                                                        const float* __restrict__ past_norm_l,
                                                        float* __restrict__ out_kv,
                                                        float* __restrict__ out_norm) {
    int bh = blockIdx.x;
    int t = threadIdx.x;
#pragma unroll
    for (int c = 0; c < 4; c++) {
        int idx = t + c * 256; // float4 index within 64x64
        float4 acc = ((const float4*)(past_kv_l + (size_t)bh * DH * DH))[idx];
        for (int ch = 0; ch < 16; ch++) {
            float4 p = ((const float4*)(part + ((size_t)bh * 16 + ch) * DH * DH))[idx];
            acc.x += p.x; acc.y += p.y; acc.z += p.z; acc.w += p.w;
        }
        ((float4*)(out_kv + (size_t)bh * DH * DH))[idx] = acc;
    }
    if (t < 16) {
        float4 acc = ((const float4*)(past_norm_l + (size_t)bh * DH))[t];
        for (int ch = 0; ch < 16; ch++) {
            float4 p = ((const float4*)(partn + ((size_t)bh * 16 + ch) * DH))[t];
            acc.x += p.x; acc.y += p.y; acc.z += p.z; acc.w += p.w;
        }
        ((float4*)(out_norm + (size_t)bh * DH))[t] = acc;
    }
}

// ---------------------------------------------------------------------------
extern "C" void kernel_launch(void* const* d_in, const int* in_sizes, int n_in,
                              void* d_out, int out_size, void* d_ws, size_t ws_size,
                              hipStream_t stream) {
    const int*   tokens      = (const int*)d_in[0];
    const float* past_kv     = (const float*)d_in[1];
    const float* past_norm   = (const float*)d_in[2];
    const float* emb         = (const float*)d_in[3];
    const float* attn_gamma  = (const float*)d_in[4];
    const float* Wqkv        = (const float*)d_in[5];
    const float* Wout        = (const float*)d_in[6];
    const float* gates       = (const float*)d_in[7];
    const float* ff_gamma    = (const float*)d_in[8];
    const float* W1          = (const float*)d_in[9];
    const float* W2          = (const float*)d_in[10];
    const float* final_gamma = (const float*)d_in[11];
    const float* Wlogits     = (const float*)d_in[12];

    float* out      = (float*)d_out;
    float* logits   = out;                                  // B*N*V
    float* out_kv   = out + (size_t)B * N * V;              // L*B*H*DH*DH
    float* out_norm = out_kv + (size_t)L * B * H * DH * DH; // L*B*H*DH

    float* ws = (float*)d_ws;
    float* X    = ws; ws += (size_t)M * D;
    float* Hb   = ws; ws += (size_t)M * D;
    float* Qh   = ws; ws += (size_t)M * D;
    float* Kh   = ws; ws += (size_t)M * D;
    float* Vh   = ws; ws += (size_t)M * D;
    float* ATT  = ws; ws += (size_t)M * D;
    float* V2   = ws; ws += (size_t)M * D;
    float* H2   = ws; ws += (size_t)M * D;
    float* FF1  = ws; ws += (size_t)M * 4 * D;  // also holds QKV (M*3D) early in layer
    float* QKV  = FF1;                          // aliased: disjoint live ranges
    float* PART = ws; ws += (size_t)32 * 16 * DH * DH;
    float* PARTN= ws; ws += (size_t)32 * 16 * DH;
    // total ~27.6M floats ~= 110 MB of d_ws

    gather_kernel<<<M, 256, 0, stream>>>(tokens, emb, X);

    for (int l = 0; l < L; l++) {
        const float* pkv = past_kv + (size_t)l * B * H * DH * DH;
        const float* pnm = past_norm + (size_t)l * B * H * DH;

        rmsnorm_kernel<<<M, 256, 0, stream>>>(X, attn_gamma + (size_t)l * D, Hb);
        gemm_kernel<0><<<dim3(3 * D / GBN, M / GBM), 256, 0, stream>>>(
            Hb, Wqkv + (size_t)l * D * 3 * D, QKV, M, 3 * D, D);
        rope_split_kernel<<<M, 256, 0, stream>>>(QKV, Qh, Kh, Vh);
        attn_kernel<<<dim3(N / 8, B * H), 256, 0, stream>>>(Qh, Kh, Vh, ATT);
        retrieve_kernel<0><<<dim3(N / 64, B * H), 256, 0, stream>>>(
            Qh, pkv, pnm, ATT, gates + (size_t)l * H, H2);
        gemm_kernel<1><<<dim3(D / GBN, M / GBM), 256, 0, stream>>>(
            H2, Wout + (size_t)l * D * D, X, M, D, D);
        rmsnorm_kernel<<<M, 256, 0, stream>>>(X, ff_gamma + (size_t)l * D, Hb);
        gemm_kernel<2><<<dim3(4 * D / GBN, M / GBM), 256, 0, stream>>>(
            Hb, W1 + (size_t)l * D * 4 * D, FF1, M, 4 * D, D);
        gemm_kernel<1><<<dim3(D / GBN, M / GBM), 256, 0, stream>>>(
            FF1, W2 + (size_t)l * 4 * D * D, X, M, D, 4 * D);
        retrieve_kernel<1><<<dim3(N / 64, B * H), 256, 0, stream>>>(
            Kh, pkv, pnm, Vh, nullptr, V2);
        newkv_partial_kernel<<<dim3(16, 32), 256, 0, stream>>>(Kh, V2, PART, PARTN);
        kv_reduce_kernel<<<32, 256, 0, stream>>>(
            PART, PARTN, pkv, pnm,
            out_kv + (size_t)l * B * H * DH * DH,
            out_norm + (size_t)l * B * H * DH);
    }

    rmsnorm_kernel<<<M, 256, 0, stream>>>(X, final_gamma, Hb);
    gemm_kernel<0><<<dim3(V / GBN, M / GBM), 256, 0, stream>>>(Hb, Wlogits, logits, M, V, D);
}

// Round 3
// 5714.277 us; speedup vs baseline: 1.9005x; 1.9005x over previous
//
#include <hip/hip_runtime.h>
#include <math.h>

// Problem constants
constexpr int V  = 32000;
constexpr int D  = 1024;
constexpr int L  = 6;
constexpr int H  = 16;
constexpr int DH = 64;
constexpr int B  = 2;
constexpr int N  = 1024;
constexpr int M  = B * N; // 2048 token rows

typedef unsigned short ushort;
typedef unsigned int uint;
typedef __bf16 bf16x8 __attribute__((ext_vector_type(8)));
typedef float f32x4 __attribute__((ext_vector_type(4)));
typedef ushort ushort8 __attribute__((ext_vector_type(8)));

// fp32 -> bf16 round-to-nearest-even
__device__ __forceinline__ ushort f2bf(float x) {
    uint u = __float_as_uint(x);
    uint r = (u + 0x7fffu + ((u >> 16) & 1u)) >> 16;
    return (ushort)r;
}
__device__ __forceinline__ float bf2f(ushort h) {
    return __uint_as_float(((uint)h) << 16);
}
// split x into hi+lo bf16
__device__ __forceinline__ void split_bf(float x, ushort& h, ushort& l) {
    h = f2bf(x);
    l = f2bf(x - bf2f(h));
}

// ---------------------------------------------------------------------------
// Embedding gather: X[row,:] = emb[tokens[row],:]
// ---------------------------------------------------------------------------
__global__ __launch_bounds__(256) void gather_kernel(const int* __restrict__ tokens,
                                                     const float* __restrict__ emb,
                                                     float* __restrict__ X) {
    int row = blockIdx.x;
    int t = threadIdx.x;
    int tok = tokens[row];
    ((float4*)(X + (size_t)row * D))[t] = ((const float4*)(emb + (size_t)tok * D))[t];
}

// ---------------------------------------------------------------------------
// RMSNorm -> (hi,lo) bf16 output pair (feeds MFMA GEMM A-side)
// ---------------------------------------------------------------------------
__global__ __launch_bounds__(256) void rmsnorm_kernel(const float* __restrict__ X,
                                                      const float* __restrict__ gamma,
                                                      ushort* __restrict__ OH,
                                                      ushort* __restrict__ OL) {
    int row = blockIdx.x;
    int t = threadIdx.x;
    float4 x = ((const float4*)(X + (size_t)row * D))[t];
    float ss = x.x * x.x + x.y * x.y + x.z * x.z + x.w * x.w;
#pragma unroll
    for (int off = 32; off; off >>= 1) ss += __shfl_xor(ss, off);
    __shared__ float red[4];
    int w = t >> 6;
    if ((t & 63) == 0) red[w] = ss;
    __syncthreads();
    ss = red[0] + red[1] + red[2] + red[3];
    float inv = rsqrtf(ss + 1e-12f) * 32.0f; // sqrt(1024)=32
    float4 g = ((const float4*)gamma)[t];
    float o0 = x.x * inv * g.x, o1 = x.y * inv * g.y, o2 = x.z * inv * g.z, o3 = x.w * inv * g.w;
    ushort4 h, l;
    split_bf(o0, h.x, l.x); split_bf(o1, h.y, l.y);
    split_bf(o2, h.z, l.z); split_bf(o3, h.w, l.w);
    *(ushort4*)(OH + (size_t)row * D + t * 4) = h;
    *(ushort4*)(OL + (size_t)row * D + t * 4) = l;
}

// ---------------------------------------------------------------------------
// Weight convert + transpose: W[K][N] fp32 -> OH/OL[N][K] bf16 hi/lo
// grid (Ndim/64, Kdim/64), 256 threads, 64x64 tile via LDS
// ---------------------------------------------------------------------------
__global__ __launch_bounds__(256) void wconv_kernel(const float* __restrict__ W,
                                                    ushort* __restrict__ OH,
                                                    ushort* __restrict__ OL,
                                                    int Kdim, int Ndim) {
    __shared__ float tile[64][65];
    int n0 = blockIdx.x * 64, k0 = blockIdx.y * 64;
    int t = threadIdx.x;
#pragma unroll
    for (int i = 0; i < 4; i++) {
        int idx = t + i * 256;
        int r = idx >> 4, c = (idx & 15) * 4;
        float4 v = *(const float4*)(W + (size_t)(k0 + r) * Ndim + n0 + c);
        tile[r][c] = v.x; tile[r][c + 1] = v.y; tile[r][c + 2] = v.z; tile[r][c + 3] = v.w;
    }
    __syncthreads();
#pragma unroll
    for (int i = 0; i < 4; i++) {
        int idx = t + i * 256;
        int nn = idx >> 4, c = (idx & 15) * 4;
        ushort4 h, l;
        split_bf(tile[c + 0][nn], h.x, l.x);
        split_bf(tile[c + 1][nn], h.y, l.y);
        split_bf(tile[c + 2][nn], h.z, l.z);
        split_bf(tile[c + 3][nn], h.w, l.w);
        *(ushort4*)(OH + (size_t)(n0 + nn) * Kdim + k0 + c) = h;
        *(ushort4*)(OL + (size_t)(n0 + nn) * Kdim + k0 + c) = l;
    }
}

// ---------------------------------------------------------------------------
// Split-bf16 MFMA GEMM: C[M,N] = (Ah+Al)[M,K] @ (Bh+Bl)[K,N] (B given transposed [N][K])
// acc += Ah*Bh + Ah*Bl + Al*Bh   (lo*lo dropped, ~4e-6 rel err)
// 128x128 tile, BK=32, 4 waves (2x2), each wave 64x64 = 4x4 frags of 16x16x32.
// EPI: 0 = store fp32, 1 = C += (residual), 2 = gelu -> (hi,lo) bf16 to CH/CL
// ---------------------------------------------------------------------------
template <int EPI>
__global__ __launch_bounds__(256) void gemm_bf16_kernel(const ushort* __restrict__ Ah,
                                                        const ushort* __restrict__ Al,
                                                        const ushort* __restrict__ Bh,
                                                        const ushort* __restrict__ Bl,
                                                        float* __restrict__ C,
                                                        ushort* __restrict__ CH,
                                                        ushort* __restrict__ CL,
                                                        int Mdim, int Ndim, int Kdim) {
    constexpr int BM = 128, BN = 128, BK = 32, PK = 40; // PK: +8 bf16 pad -> 2-way max conflicts
    __shared__ ushort Ash[BM * PK], Asl[BM * PK], Bsh[BN * PK], Bsl[BN * PK]; // 40 KB

    int t = threadIdx.x;
    int lane = t & 63, w = t >> 6;
    int wr = w >> 1, wc = w & 1;
    int m0 = blockIdx.y * BM, n0 = blockIdx.x * BN;

    f32x4 acc[4][4];
#pragma unroll
    for (int i = 0; i < 4; i++)
#pragma unroll
        for (int j = 0; j < 4; j++) acc[i][j] = (f32x4){0.f, 0.f, 0.f, 0.f};

    int arow = wr * 64 + (lane & 15);
    int brow = wc * 64 + (lane & 15);
    int koff = (lane >> 4) * 8;

    for (int k0 = 0; k0 < Kdim; k0 += BK) {
        __syncthreads();
        // stage: 512 16B-chunks per matrix, 2 per thread
#pragma unroll
        for (int i = 0; i < 2; i++) {
            int chunk = t + i * 256;
            int r = chunk >> 2, off = (chunk & 3) * 8;
            ushort8 a0 = *(const ushort8*)(Ah + (size_t)(m0 + r) * Kdim + k0 + off);
            ushort8 a1 = *(const ushort8*)(Al + (size_t)(m0 + r) * Kdim + k0 + off);
            ushort8 b0 = *(const ushort8*)(Bh + (size_t)(n0 + r) * Kdim + k0 + off);
            ushort8 b1 = *(const ushort8*)(Bl + (size_t)(n0 + r) * Kdim + k0 + off);
            *(ushort8*)&Ash[r * PK + off] = a0;
            *(ushort8*)&Asl[r * PK + off] = a1;
            *(ushort8*)&Bsh[r * PK + off] = b0;
            *(ushort8*)&Bsl[r * PK + off] = b1;
        }
        __syncthreads();

        bf16x8 fah[4], fal[4], fbh[4], fbl[4];
#pragma unroll
        for (int i = 0; i < 4; i++) {
            fah[i] = *(const bf16x8*)&Ash[(arow + i * 16) * PK + koff];
            fal[i] = *(const bf16x8*)&Asl[(arow + i * 16) * PK + koff];
        }
#pragma unroll
        for (int j = 0; j < 4; j++) {
            fbh[j] = *(const bf16x8*)&Bsh[(brow + j * 16) * PK + koff];
            fbl[j] = *(const bf16x8*)&Bsl[(brow + j * 16) * PK + koff];
        }
#pragma unroll
        for (int i = 0; i < 4; i++)
#pragma unroll
            for (int j = 0; j < 4; j++) {
                acc[i][j] = __builtin_amdgcn_mfma_f32_16x16x32_bf16(fah[i], fbh[j], acc[i][j], 0, 0, 0);
                acc[i][j] = __builtin_amdgcn_mfma_f32_16x16x32_bf16(fah[i], fbl[j], acc[i][j], 0, 0, 0);
                acc[i][j] = __builtin_amdgcn_mfma_f32_16x16x32_bf16(fal[i], fbh[j], acc[i][j], 0, 0, 0);
            }
    }

    // Epilogue. C/D layout: col = lane&15, row = (lane>>4)*4 + q  [m89-verified]
    int crow = m0 + wr * 64 + (lane >> 4) * 4;
    int ccol = n0 + wc * 64 + (lane & 15);
#pragma unroll
    for (int i = 0; i < 4; i++)
#pragma unroll
        for (int q = 0; q < 4; q++) {
            int r = crow + i * 16 + q;
#pragma unroll
            for (int j = 0; j < 4; j++) {
                float v = acc[i][j][q];
                size_t cidx = (size_t)r * Ndim + ccol + j * 16;
                if (EPI == 0) {
                    C[cidx] = v;
                } else if (EPI == 1) {
                    C[cidx] += v;
                } else {
                    float ge = 0.5f * v * (1.f + erff(v * 0.70710678118654752f));
                    ushort h, l;
                    split_bf(ge, h, l);
                    CH[cidx] = h;
                    CL[cidx] = l;
                }
            }
        }
}

// ---------------------------------------------------------------------------
// RoPE + split heads: QKV (M x 3072) -> Qh, Kh (rotated), Vh in (B*H, N, DH) layout
// ---------------------------------------------------------------------------
__global__ __launch_bounds__(256) void rope_split_kernel(const float* __restrict__ QKV,
                                                         float* __restrict__ Qh,
                                                         float* __restrict__ Kh,
                                                         float* __restrict__ Vh) {
    int row = blockIdx.x; // b*N + n
    int n = row & (N - 1);
    int b = row >> 10;
    int t = threadIdx.x;
    const float* src = QKV + (size_t)row * (3 * D);

    // V copy
    {
        float4 v4 = ((const float4*)(src + 2 * D))[t];
        int h = t >> 4;
        int d = (t & 15) * 4;
        *(float4*)(Vh + ((size_t)(b * H + h) * N + n) * DH + d) = v4;
    }
#pragma unroll
    for (int i = 0; i < 2; i++) {
        int p = t + i * 256; // 0..511
        int hh = p >> 5;
        int pi = p & 31;
        float inv = __expf(-(float)pi * (9.210340371976184f / 32.0f)); // 10000^(-pi/32)
        float ang = (float)n * inv;
        float s, c;
        __sincosf(ang, &s, &c);
        {
            float q0 = src[hh * DH + 2 * pi];
            float q1 = src[hh * DH + 2 * pi + 1];
            float* qd = Qh + ((size_t)(b * H + hh) * N + n) * DH;
            qd[2 * pi]     = q0 * c - q1 * s;
            qd[2 * pi + 1] = q1 * c + q0 * s;
        }
        {
            float k0 = src[D + hh * DH + 2 * pi];
            float k1 = src[D + hh * DH + 2 * pi + 1];
            float* kd = Kh + ((size_t)(b * H + hh) * N + n) * DH;
            kd[2 * pi]     = k0 * c - k1 * s;
            kd[2 * pi + 1] = k1 * c + k0 * s;
        }
    }
}

// ---------------------------------------------------------------------------
// Attention: per block = one (b,h) and a tile of TQ=8 q rows, full softmax over N keys.
// ---------------------------------------------------------------------------
__global__ __launch_bounds__(256) void attn_kernel(const float* __restrict__ Q,
                                                   const float* __restrict__ K,
                                                   const float* __restrict__ Vv,
                                                   float* __restrict__ O) {
    constexpr int TQ = 8;
    __shared__ float qs[TQ][DH];
    __shared__ float sc[TQ][N];
    __shared__ float rs[TQ];
    int bh = blockIdx.y;
    int n0 = blockIdx.x * TQ;
    int t = threadIdx.x;
    const float* Qb = Q + ((size_t)bh * N + n0) * DH;
    const float* Kb = K + (size_t)bh * N * DH;
    const float* Vb = Vv + (size_t)bh * N * DH;

    if (t < TQ * DH / 4) ((float4*)qs)[t] = ((const float4*)Qb)[t];
    __syncthreads();

#pragma unroll
    for (int kp = 0; kp < 2; kp++) {
        int j0 = t * 4 + kp * 2;
        const float4* k0p = (const float4*)(Kb + (size_t)j0 * DH);
        const float4* k1p = k0p + (DH / 4);
        float acc0[TQ], acc1[TQ];
#pragma unroll
        for (int r = 0; r < TQ; r++) { acc0[r] = 0.f; acc1[r] = 0.f; }
#pragma unroll
        for (int dc = 0; dc < DH / 4; dc++) {
            float4 kv0 = k0p[dc];
            float4 kv1 = k1p[dc];
#pragma unroll
            for (int r = 0; r < TQ; r++) {
                float4 q4 = *(const float4*)&qs[r][dc * 4];
                acc0[r] = fmaf(q4.x, kv0.x, fmaf(q4.y, kv0.y, fmaf(q4.z, kv0.z, fmaf(q4.w, kv0.w, acc0[r]))));
                acc1[r] = fmaf(q4.x, kv1.x, fmaf(q4.y, kv1.y, fmaf(q4.z, kv1.z, fmaf(q4.w, kv1.w, acc1[r]))));
            }
        }
#pragma unroll
        for (int r = 0; r < TQ; r++) {
            sc[r][j0] = acc0[r] * 0.125f;
            sc[r][j0 + 1] = acc1[r] * 0.125f;
        }
    }
    __syncthreads();

    {
        int r = t >> 5, g = t & 31;
        float4* srow = (float4*)&sc[r][0];
        float mx = -1e30f;
#pragma unroll
        for (int c = 0; c < 8; c++) {
            float4 v = srow[g + c * 32];
            mx = fmaxf(mx, fmaxf(fmaxf(v.x, v.y), fmaxf(v.z, v.w)));
        }
#pragma unroll
        for (int off = 16; off; off >>= 1) mx = fmaxf(mx, __shfl_xor(mx, off, 32));
        float sum = 0.f;
#pragma unroll
        for (int c = 0; c < 8; c++) {
            float4 v = srow[g + c * 32];
            v.x = __expf(v.x - mx);
            v.y = __expf(v.y - mx);
            v.z = __expf(v.z - mx);
            v.w = __expf(v.w - mx);
            sum += v.x + v.y + v.z + v.w;
            srow[g + c * 32] = v;
        }
#pragma unroll
        for (int off = 16; off; off >>= 1) sum += __shfl_xor(sum, off, 32);
        if (g == 0) rs[r] = sum;
    }
    __syncthreads();

    {
        int d = t & 63, w = t >> 6;
        float a0 = 0.f, a1 = 0.f;
        for (int jc = 0; jc < N / 4; jc++) {
            float4 p0 = *(const float4*)&sc[w][jc * 4];
            float4 p1 = *(const float4*)&sc[w + 4][jc * 4];
            const float* vp = Vb + (size_t)jc * 4 * DH + d;
            float v0 = vp[0], v1 = vp[DH], v2 = vp[2 * DH], v3 = vp[3 * DH];
            a0 += p0.x * v0 + p0.y * v1 + p0.z * v2 + p0.w * v3;
            a1 += p1.x * v0 + p1.y * v1 + p1.z * v2 + p1.w * v3;
        }
        O[((size_t)bh * N + n0 + w) * DH + d] = a0 / rs[w];
        O[((size_t)bh * N + n0 + w + 4) * DH + d] = a1 / rs[w + 4];
    }
}

// ---------------------------------------------------------------------------
// retrieve(feat, mem_kv, mem_norm) with elu(x)+1 applied on the fly.
// MODE 0: gate-fused output written as (hi,lo) bf16 in B,N,D layout (feeds Wout GEMM)
// MODE 1: out fp32 head layout = V - retrieve(kf)
// ---------------------------------------------------------------------------
template <int MODE>
__global__ __launch_bounds__(256) void retrieve_kernel(const float* __restrict__ F,
                                                       const float* __restrict__ mem_kv,
                                                       const float* __restrict__ mem_norm,
                                                       const float* __restrict__ AuxIn,
                                                       const float* __restrict__ gates_l,
                                                       float* __restrict__ outp,
                                                       ushort* __restrict__ outH,
                                                       ushort* __restrict__ outL) {
    int bh = blockIdx.y;
    int n0 = blockIdx.x * 64;
    int b = bh / H, h = bh % H;
    __shared__ float mk[DH][DH];
    __shared__ float ff[64][DH];
    __shared__ float mn[DH], den[64];
    int t = threadIdx.x;

#pragma unroll
    for (int i = 0; i < 4; i++) {
        int idx = t + i * 256;
        float4 v = ((const float4*)(mem_kv + (size_t)bh * DH * DH))[idx];
        *(float4*)&mk[idx >> 4][(idx & 15) * 4] = v;
    }
    if (t < DH / 4) ((float4*)mn)[t] = ((const float4*)(mem_norm + (size_t)bh * DH))[t];
#pragma unroll
    for (int i = 0; i < 4; i++) {
        int idx = t + i * 256;
        int r = idx >> 4, c4 = (idx & 15) * 4;
        float4 v = *(const float4*)(F + ((size_t)bh * N + n0 + r) * DH + c4);
        v.x = v.x > 0.f ? v.x + 1.f : __expf(v.x);
        v.y = v.y > 0.f ? v.y + 1.f : __expf(v.y);
        v.z = v.z > 0.f ? v.z + 1.f : __expf(v.z);
        v.w = v.w > 0.f ? v.w + 1.f : __expf(v.w);
        *(float4*)&ff[r][c4] = v;
    }
    __syncthreads();
    if (t < 64) {
        float s = 0.f;
        for (int dd = 0; dd < DH; dd++) s += ff[t][dd] * mn[dd];
        den[t] = fmaxf(s, 1e-10f);
    }
    __syncthreads();

    int e = t & 63, w = t >> 6;
    float g = 0.f;
    if (MODE == 0) g = 1.f / (1.f + __expf(-gates_l[h]));
#pragma unroll 4
    for (int i = 0; i < 16; i++) {
        int nn = w + i * 4;
        float acc = 0.f;
        for (int dd = 0; dd < DH; dd++) acc = fmaf(ff[nn][dd], mk[dd][e], acc);
        float val = acc / den[nn];
        if (MODE == 0) {
            float a = AuxIn[((size_t)bh * N + n0 + nn) * DH + e];
            float o = a * g + val * (1.f - g);
            ushort hh, ll;
            split_bf(o, hh, ll);
            size_t oidx = ((size_t)(b * N + n0 + nn)) * D + h * DH + e;
            outH[oidx] = hh;
            outL[oidx] = ll;
        } else {
            float vv = AuxIn[((size_t)bh * N + n0 + nn) * DH + e];
            outp[((size_t)bh * N + n0 + nn) * DH + e] = vv - val;
        }
    }
}

// ---------------------------------------------------------------------------
// new_kv partials: kf^T @ v2 per 64-chunk, plus sum_n kf
// ---------------------------------------------------------------------------
__global__ __launch_bounds__(256) void newkv_partial_kernel(const float* __restrict__ Kh,
                                                            const float* __restrict__ V2,
                                                            float* __restrict__ part,
                                                            float* __restrict__ partn) {
    int bh = blockIdx.y;
    int chunk = blockIdx.x;
    int n0 = chunk * 64;
    __shared__ float kf[64][DH];
    __shared__ float vs[64][DH];
    int t = threadIdx.x;
#pragma unroll
    for (int i = 0; i < 4; i++) {
        int idx = t + i * 256;
        int r = idx >> 4, c4 = (idx & 15) * 4;
        float4 v = *(const float4*)(Kh + ((size_t)bh * N + n0 + r) * DH + c4);
        v.x = v.x > 0.f ? v.x + 1.f : __expf(v.x);
        v.y = v.y > 0.f ? v.y + 1.f : __expf(v.y);
        v.z = v.z > 0.f ? v.z + 1.f : __expf(v.z);
        v.w = v.w > 0.f ? v.w + 1.f : __expf(v.w);
        *(float4*)&kf[r][c4] = v;
        float4 u = *(const float4*)(V2 + ((size_t)bh * N + n0 + r) * DH + c4);
        *(float4*)&vs[r][c4] = u;
    }
    __syncthreads();
    int e = t & 63, w = t >> 6;
    int d0 = w * 16;
    float acc[16];
#pragma unroll
    for (int i = 0; i < 16; i++) acc[i] = 0.f;
    for (int nn = 0; nn < 64; nn++) {
        float vv = vs[nn][e];
#pragma unroll
        for (int i = 0; i < 16; i++) acc[i] = fmaf(kf[nn][d0 + i], vv, acc[i]);
    }
    float* pp = part + ((size_t)bh * 16 + chunk) * DH * DH;
#pragma unroll
    for (int i = 0; i < 16; i++) pp[(size_t)(d0 + i) * DH + e] = acc[i];
    if (t < 64) {
        float s = 0.f;
        for (int nn = 0; nn < 64; nn++) s += kf[nn][t];
        partn[((size_t)bh * 16 + chunk) * DH + t] = s;
    }
}

// ---------------------------------------------------------------------------
// reduce partials + past -> outputs
// ---------------------------------------------------------------------------
__global__ __launch_bounds__(256) void kv_reduce_kernel(const float* __restrict__ part,
                                                        const float* __restrict__ partn,
                                                        const float* __restrict__ past_kv_l,
                                                        const float* __restrict__ past_norm_l,
                                                        float* __restrict__ out_kv,
                                                        float* __restrict__ out_norm) {
    int bh = blockIdx.x;
    int t = threadIdx.x;
#pragma unroll
    for (int c = 0; c < 4; c++) {
        int idx = t + c * 256;
        float4 acc = ((const float4*)(past_kv_l + (size_t)bh * DH * DH))[idx];
        for (int ch = 0; ch < 16; ch++) {
            float4 p = ((const float4*)(part + ((size_t)bh * 16 + ch) * DH * DH))[idx];
            acc.x += p.x; acc.y += p.y; acc.z += p.z; acc.w += p.w;
        }
        ((float4*)(out_kv + (size_t)bh * DH * DH))[idx] = acc;
    }
    if (t < 16) {
        float4 acc = ((const float4*)(past_norm_l + (size_t)bh * DH))[t];
        for (int ch = 0; ch < 16; ch++) {
            float4 p = ((const float4*)(partn + ((size_t)bh * 16 + ch) * DH))[t];
            acc.x += p.x; acc.y += p.y; acc.z += p.z; acc.w += p.w;
        }
        ((float4*)(out_norm + (size_t)bh * DH))[t] = acc;
    }
}

// ---------------------------------------------------------------------------
extern "C" void kernel_launch(void* const* d_in, const int* in_sizes, int n_in,
                              void* d_out, int out_size, void* d_ws, size_t ws_size,
                              hipStream_t stream) {
    const int*   tokens      = (const int*)d_in[0];
    const float* past_kv     = (const float*)d_in[1];
    const float* past_norm   = (const float*)d_in[2];
    const float* emb         = (const float*)d_in[3];
    const float* attn_gamma  = (const float*)d_in[4];
    const float* Wqkv        = (const float*)d_in[5];
    const float* Wout        = (const float*)d_in[6];
    const float* gates       = (const float*)d_in[7];
    const float* ff_gamma    = (const float*)d_in[8];
    const float* W1          = (const float*)d_in[9];
    const float* W2          = (const float*)d_in[10];
    const float* final_gamma = (const float*)d_in[11];
    const float* Wlogits     = (const float*)d_in[12];

    float* out      = (float*)d_out;
    float* logits   = out;                                  // B*N*V
    float* out_kv   = out + (size_t)B * N * V;              // L*B*H*DH*DH
    float* out_norm = out_kv + (size_t)L * B * H * DH * DH; // L*B*H*DH

    // ---- workspace carve (fp32 first, then bf16) ----
    float* ws = (float*)d_ws;
    float* X    = ws; ws += (size_t)M * D;        // 2.1M
    float* QKV  = ws; ws += (size_t)M * 3 * D;    // 6.3M
    float* Qh   = ws; ws += (size_t)M * D;
    float* Kh   = ws; ws += (size_t)M * D;
    float* Vh   = ws; ws += (size_t)M * D;
    float* ATT  = ws; ws += (size_t)M * D;
    float* V2   = ws; ws += (size_t)M * D;
    float* PART = ws; ws += (size_t)32 * 16 * DH * DH;
    float* PARTN= ws; ws += (size_t)32 * 16 * DH;

    ushort* us = (ushort*)ws;
    ushort* HbH = us; us += (size_t)M * D;
    ushort* HbL = us; us += (size_t)M * D;
    ushort* H2H = us; us += (size_t)M * D;
    ushort* H2L = us; us += (size_t)M * D;
    ushort* FF1H = us; us += (size_t)M * 4 * D;
    ushort* FF1L = us; us += (size_t)M * 4 * D;
    ushort* WTH = us; us += (size_t)V * D;        // 32.77M (holds layer weights or Wlogits^T)
    ushort* WTL = us; us += (size_t)V * D;
    // layer-weight sub-offsets within WTH/WTL
    const size_t OQ = 0;                       // Wqkv^T  : 3072*1024
    const size_t OO = (size_t)3072 * 1024;     // Wout^T  : 1024*1024
    const size_t O1 = OO + (size_t)1024 * 1024;// W1^T    : 4096*1024
    const size_t O2 = O1 + (size_t)4096 * 1024;// W2^T    : 1024*4096
    // total ws ~= 265 MB

    gather_kernel<<<M, 256, 0, stream>>>(tokens, emb, X);

    for (int l = 0; l < L; l++) {
        const float* pkv = past_kv + (size_t)l * B * H * DH * DH;
        const float* pnm = past_norm + (size_t)l * B * H * DH;

        // weight convert+transpose for this layer
        wconv_kernel<<<dim3(3 * D / 64, D / 64), 256, 0, stream>>>(
            Wqkv + (size_t)l * D * 3 * D, WTH + OQ, WTL + OQ, D, 3 * D);
        wconv_kernel<<<dim3(D / 64, D / 64), 256, 0, stream>>>(
            Wout + (size_t)l * D * D, WTH + OO, WTL + OO, D, D);
        wconv_kernel<<<dim3(4 * D / 64, D / 64), 256, 0, stream>>>(
            W1 + (size_t)l * D * 4 * D, WTH + O1, WTL + O1, D, 4 * D);
        wconv_kernel<<<dim3(D / 64, 4 * D / 64), 256, 0, stream>>>(
            W2 + (size_t)l * 4 * D * D, WTH + O2, WTL + O2, 4 * D, D);

        rmsnorm_kernel<<<M, 256, 0, stream>>>(X, attn_gamma + (size_t)l * D, HbH, HbL);
        gemm_bf16_kernel<0><<<dim3(3 * D / 128, M / 128), 256, 0, stream>>>(
            HbH, HbL, WTH + OQ, WTL + OQ, QKV, nullptr, nullptr, M, 3 * D, D);
        rope_split_kernel<<<M, 256, 0, stream>>>(QKV, Qh, Kh, Vh);
        attn_kernel<<<dim3(N / 8, B * H), 256, 0, stream>>>(Qh, Kh, Vh, ATT);
        retrieve_kernel<0><<<dim3(N / 64, B * H), 256, 0, stream>>>(
            Qh, pkv, pnm, ATT, gates + (size_t)l * H, nullptr, H2H, H2L);
        gemm_bf16_kernel<1><<<dim3(D / 128, M / 128), 256, 0, stream>>>(
            H2H, H2L, WTH + OO, WTL + OO, X, nullptr, nullptr, M, D, D);
        rmsnorm_kernel<<<M, 256, 0, stream>>>(X, ff_gamma + (size_t)l * D, HbH, HbL);
        gemm_bf16_kernel<2><<<dim3(4 * D / 128, M / 128), 256, 0, stream>>>(
            HbH, HbL, WTH + O1, WTL + O1, nullptr, FF1H, FF1L, M, 4 * D, D);
        gemm_bf16_kernel<1><<<dim3(D / 128, M / 128), 256, 0, stream>>>(
            FF1H, FF1L, WTH + O2, WTL + O2, X, nullptr, nullptr, M, D, 4 * D);
        retrieve_kernel<1><<<dim3(N / 64, B * H), 256, 0, stream>>>(
            Kh, pkv, pnm, Vh, nullptr, V2, nullptr, nullptr);
        newkv_partial_kernel<<<dim3(16, 32), 256, 0, stream>>>(Kh, V2, PART, PARTN);
        kv_reduce_kernel<<<32, 256, 0, stream>>>(
            PART, PARTN, pkv, pnm,
            out_kv + (size_t)l * B * H * DH * DH,
            out_norm + (size_t)l * B * H * DH);
    }

    rmsnorm_kernel<<<M, 256, 0, stream>>>(X, final_gamma, HbH, HbL);
    wconv_kernel<<<dim3(V / 64, D / 64), 256, 0, stream>>>(Wlogits, WTH, WTL, D, V);
    gemm_bf16_kernel<0><<<dim3(V / 128, M / 128), 256, 0, stream>>>(
        HbH, HbL, WTH, WTL, logits, nullptr, nullptr, M, V, D);
}